// Round 12
// baseline (53.982 us; speedup 1.0000x reference)
//
#include <hip/hip_runtime.h>
#include <float.h>

#define BB 32
#define CC 128
#define HH 64
#define WW 64

// async global->LDS, 16B/lane (1KB per wave-instruction), zero VGPR round-trip
#define GLDS(g, l) \
  __builtin_amdgcn_global_load_lds((const __attribute__((address_space(1))) void*)(g), \
                                   (__attribute__((address_space(3))) void*)(l), 16, 0, 0)

// Block = 256 thr = 4 waves; covers channel pair (2cp, 2cp+1) of one (b, lmi).
// Slow path: stage both channels' row-windows via global_load_lds (all loads
// in flight -> ONE stall group), then per-wave bin-max + cell-max from LDS.
// Grid = 32 b (fastest) * 8 lmi * 64 cp = 16384 blocks.
__global__ __launch_bounds__(256) void roipool_kernel(
    const float* __restrict__ x,   // [B,C,64,64]
    const float* __restrict__ lm,  // [B,16]
    float* __restrict__ out)       // [B,C,32,16]
{
    int blk = blockIdx.x;
    int b   = blk & 31;
    int lmi = (blk >> 5) & 7;
    int cp  = blk >> 8;            // 0..63
    int c0  = cp * 2;

    int tid  = threadIdx.x;
    int wave = tid >> 6;
    int lane = tid & 63;

    __shared__ float s[2][64][64];   // 32 KB: two staged channel windows
    __shared__ float tb[2][8][66];   // 4.2 KB: bin-max (padded)

    float x0 = lm[b * 16 + 2 * lmi];
    float y0 = lm[b * 16 + 2 * lmi + 1];
    bool visible = (x0 > 0.0f) || (y0 > 0.0f);

    // torchvision column-swap semantics:
    // rois=(b,x1,x2,y1,y2) consumed as (b,start_w,start_h,end_w,end_h)
    int fx = (int)floorf(x0 * 0.25f);
    int fy = (int)floorf(y0 * 0.25f);
    int roi = max(fy - fx + 1, 1);      // roi_w == roi_h
    float bin = (float)roi * 0.125f;    // exact /8

    const float* __restrict__ xpA = x + ((size_t)(b * CC + c0) << 12);
    const float* __restrict__ xpB = xpA + (1 << 12);

    // ---------- fast path: !visible -> zeros; roi==1 -> single pixel ----------
    if (!visible || roi == 1) {         // block-uniform
        if (wave < 2) {
            const float* xp = wave ? xpB : xpA;
            int i = lane >> 3, j = lane & 7;
            int hs = min(max(fx, 0), HH),     he = min(max(fx + 1, 0), HH);
            int ws = min(max(fx - 7, 0), WW), we = min(max(fx - 6, 0), WW);
            bool empty = (he <= hs) || (we <= ws) || !visible;
            float v = empty ? 0.0f : xp[(hs << 6) + ws];
            int orow = 8 * (lmi >> 1) + i, ocol = 8 * (lmi & 1) + j;
            out[(((size_t)(b * CC + c0 + wave)) * 32 + orow) * 16 + ocol] = v;
        }
        return;
    }

    int h0 = min(max(fx, 0), HH);
    int h1 = min(max(fx + roi, 0), HH);
    int Hwin = h1 - h0;                 // 0..64
    int G = (Hwin + 3) >> 2;            // 1KB row-groups per channel

    // ---- stage 0: all groups issued before any use -> one stall group ----
    int rl  = lane >> 4;                // sub-row 0..3
    int cql = (lane & 15) << 2;         // col (floats)
    for (int idx = wave; idx < 2 * G; idx += 4) {
        int ch = (idx >= G) ? 1 : 0;
        int k  = idx - ch * G;
        int r  = min(h0 + 4 * k + rl, h1 - 1);   // clamped dup rows land in
        const float* g = (ch ? xpB : xpA) + (r << 6) + cql;  // never-read slots
        GLDS(g, &s[ch][4 * k][0]);
    }
    __syncthreads();   // compiler drains vmcnt(0) here

    // ---- stage 1: wave -> (ch = wave>>1, bins tbase..tbase+3); lane = col ----
    int ch    = wave >> 1;
    int tbase = (wave & 1) * 4;
    #pragma unroll
    for (int tt = 0; tt < 4; ++tt) {
        int t  = tbase + tt;
        int hs = min(max((int)floorf((float)t * bin) + fx, 0), HH);
        int he = min(max((int)ceilf((float)(t + 1) * bin) + fx, 0), HH);
        float acc = -FLT_MAX;
        for (int h = hs; h < he; h += 4) {
            int hm = he - 1;            // clamped dups harmless under max
            float a0 = s[ch][h - h0][lane];
            float a1 = s[ch][min(h + 1, hm) - h0][lane];
            float a2 = s[ch][min(h + 2, hm) - h0][lane];
            float a3 = s[ch][min(h + 3, hm) - h0][lane];
            acc = fmaxf(acc, fmaxf(fmaxf(a0, a1), fmaxf(a2, a3)));
        }
        tb[ch][t][lane] = acc;          // rows 64-float -> 2 lanes/bank (free)
    }

    // ---- stage 2: same wave pools its own bins (in-order LDS, no barrier) ----
    if (lane < 32) {
        int i = tbase + (lane >> 3);
        int j = lane & 7;
        int hs = min(max((int)floorf((float)i * bin) + fx, 0), HH);
        int he = min(max((int)ceilf((float)(i + 1) * bin) + fx, 0), HH);
        int ws = min(max((int)floorf((float)j * bin) + fx - 7, 0), WW);
        int we = min(max((int)ceilf((float)(j + 1) * bin) + fx - 7, 0), WW);
        bool empty = (he <= hs) || (we <= ws);
        float m = -FLT_MAX;
        if (!empty) {
            for (int w = ws; w < we; ++w)
                m = fmaxf(m, tb[ch][i][w]);
        }
        int orow = 8 * (lmi >> 1) + i, ocol = 8 * (lmi & 1) + j;
        out[(((size_t)(b * CC + c0 + ch)) * 32 + orow) * 16 + ocol] = empty ? 0.0f : m;
    }
}

extern "C" void kernel_launch(void* const* d_in, const int* in_sizes, int n_in,
                              void* d_out, int out_size, void* d_ws, size_t ws_size,
                              hipStream_t stream) {
    const float* x  = (const float*)d_in[0];
    const float* lm = (const float*)d_in[1];
    float* out = (float*)d_out;

    int blocks = BB * 8 * 64;   // 16384
    roipool_kernel<<<blocks, 256, 0, stream>>>(x, lm, out);
}

// Round 13
// 22.224 us; speedup vs baseline: 2.4290x; 2.4290x over previous
//
#include <hip/hip_runtime.h>
#include <float.h>

#define BB 32
#define CC 128
#define HH 64
#define WW 64

// R5 structure (best known: 24.7us), instruction-minimized:
//  - float4 loads: lane=(ch,colquad); 1 instr = 4 channels x 256B row segment
//  - integer bin bounds: floor(t*roi/8) = (t*roi)>>3, ceil = (+7)>>3 (exact)
//  - float4 LDS writes for stage-1 results
// Block = 256 thr = 4 waves; wave w: bins {2w,2w+1} x 4 channels (stage 1),
// then channel w x 64 cells (stage 2). Grid = 32 b (fastest) * 8 * 32 = 8192.
__global__ __launch_bounds__(256) void roipool_kernel(
    const float* __restrict__ x,   // [B,C,64,64]
    const float* __restrict__ lm,  // [B,16]
    float* __restrict__ out)       // [B,C,32,16]
{
    int blk = blockIdx.x;
    int b   = blk & 31;
    int lmi = (blk >> 5) & 7;
    int cg  = blk >> 8;          // 0..31

    int tid  = threadIdx.x;
    int wave = tid >> 6;
    int lane = tid & 63;

    __shared__ float s[4][8][68];   // [ch][bin][col]; 68: pad, rows 16B-aligned

    float x0 = lm[b * 16 + 2 * lmi];
    float y0 = lm[b * 16 + 2 * lmi + 1];
    bool visible = (x0 > 0.0f) || (y0 > 0.0f);

    // torchvision column-swap semantics:
    // rois=(b,x1,x2,y1,y2) consumed as (b,start_w,start_h,end_w,end_h)
    int fx = (int)floorf(x0 * 0.25f);
    int fy = (int)floorf(y0 * 0.25f);
    int roi = max(fy - fx + 1, 1);      // roi_w == roi_h

    int cbase = cg * 4;
    int i = lane >> 3;   // cell row
    int j = lane & 7;    // cell col
    int orow = 8 * (lmi >> 1) + i;
    int ocol = 8 * (lmi & 1) + j;

    // ---------- fast path: roi==1 -> every cell is pixel (fx, fx-7) ----------
    if (roi == 1) {                     // block-uniform branch
        int hs = min(max(fx, 0), HH),     he = min(max(fx + 1, 0), HH);
        int ws = min(max(fx - 7, 0), WW), we = min(max(fx - 6, 0), WW);
        bool empty = (he <= hs) || (we <= ws) || !visible;
        size_t c = (size_t)(cbase + wave);
        float v = 0.0f;
        if (!empty) v = x[(((size_t)b * CC + c) << 12) + (hs << 6) + ws];
        out[(((size_t)b * CC + c) * 32 + orow) * 16 + ocol] = empty ? 0.0f : v;
        return;
    }

    // clipped column window and its quad range
    int w0 = max(fx - 7, 0);
    int w1 = min(fx - 7 + roi, WW);
    int q0 = w0 >> 2;
    int q1 = (w1 - 1) >> 2;             // inclusive; negative if w1<=0

    int ch2 = lane >> 4;                // channel 0..3 within group
    int cq  = lane & 15;                // column quad 0..15

    const float* __restrict__ xq =
        x + (((size_t)b * CC + cbase + ch2) << 12) + (cq << 2);

    // ---- stage 1: wave w -> bins 2w,2w+1 for all 4 channels; float4 cols ----
    if (visible && cq >= q0 && cq <= q1) {
        #pragma unroll
        for (int tt = 0; tt < 2; ++tt) {
            int t  = 2 * wave + tt;
            int hs = min(max(((t * roi) >> 3) + fx, 0), HH);
            int he = min(max((((t + 1) * roi + 7) >> 3) + fx, 0), HH);
            float a0 = -FLT_MAX, a1 = -FLT_MAX, a2 = -FLT_MAX, a3 = -FLT_MAX;
            for (int h = hs; h < he; h += 4) {
                int hm = he - 1;        // clamped dup rows harmless under max
                float4 v0 = *(const float4*)(xq + (h << 6));
                float4 v1 = *(const float4*)(xq + (min(h + 1, hm) << 6));
                float4 v2 = *(const float4*)(xq + (min(h + 2, hm) << 6));
                float4 v3 = *(const float4*)(xq + (min(h + 3, hm) << 6));
                a0 = fmaxf(a0, fmaxf(fmaxf(v0.x, v1.x), fmaxf(v2.x, v3.x)));
                a1 = fmaxf(a1, fmaxf(fmaxf(v0.y, v1.y), fmaxf(v2.y, v3.y)));
                a2 = fmaxf(a2, fmaxf(fmaxf(v0.z, v1.z), fmaxf(v2.z, v3.z)));
                a3 = fmaxf(a3, fmaxf(fmaxf(v0.w, v1.w), fmaxf(v2.w, v3.w)));
            }
            *(float4*)&s[ch2][t][cq << 2] = make_float4(a0, a1, a2, a3);
        }
    }
    __syncthreads();

    // ---- stage 2: wave pools channel=wave; thread = cell (i,j) ----
    int hs = min(max(((i * roi) >> 3) + fx, 0), HH);
    int he = min(max((((i + 1) * roi + 7) >> 3) + fx, 0), HH);
    int ws = min(max(((j * roi) >> 3) + fx - 7, 0), WW);
    int we = min(max((((j + 1) * roi + 7) >> 3) + fx - 7, 0), WW);
    bool empty = (he <= hs) || (we <= ws) || !visible;

    float m = -FLT_MAX;
    if (!empty) {
        for (int w = ws; w < we; ++w)   // [ws,we) within written quads
            m = fmaxf(m, s[wave][i][w]);
    }
    out[(((size_t)b * CC + cbase + wave) * 32 + orow) * 16 + ocol] = empty ? 0.0f : m;
}

extern "C" void kernel_launch(void* const* d_in, const int* in_sizes, int n_in,
                              void* d_out, int out_size, void* d_ws, size_t ws_size,
                              hipStream_t stream) {
    const float* x  = (const float*)d_in[0];
    const float* lm = (const float*)d_in[1];
    float* out = (float*)d_out;

    int blocks = BB * 8 * 32;   // 8192
    roipool_kernel<<<blocks, 256, 0, stream>>>(x, lm, out);
}